// Round 1
// baseline (101.942 us; speedup 1.0000x reference)
//
#include <hip/hip_runtime.h>

// PoseLoss: pred_points = model_points @ R^T + t; NN(pred, targets) for
// symmetric ids {0,7,12,20}; loss = mean_b mean_n ||pred - tgt||.
// B=128, N=1000, all fp32, scalar fp32 output.

#define BATCH 128
#define NPTS  1000
#define SPLIT 4
#define PTS_PER_BLK ((NPTS + SPLIT - 1) / SPLIT)   // 250
#define THREADS 256

__global__ __launch_bounds__(THREADS) void pose_loss_kernel(
    const float* __restrict__ pred_r,        // [B,3,3]
    const float* __restrict__ pred_t,        // [B,1,3]
    const float* __restrict__ targets,       // [B,N,3]
    const float* __restrict__ model_points,  // [B,N,3]
    const int*   __restrict__ idxs,          // [B]
    float* __restrict__ out)                 // [1]
{
    const int b   = blockIdx.x / SPLIT;
    const int s   = blockIdx.x % SPLIT;
    const int tid = threadIdx.x;

    // block-uniform symmetric check
    const int id = idxs[b];
    const bool sym = (id == 0) | (id == 7) | (id == 12) | (id == 20);

    // batch-uniform R, t -> scalar loads
    const float* Rb = pred_r + b * 9;
    const float* Tb = pred_t + b * 3;
    const float R00 = Rb[0], R01 = Rb[1], R02 = Rb[2];
    const float R10 = Rb[3], R11 = Rb[4], R12 = Rb[5];
    const float R20 = Rb[6], R21 = Rb[7], R22 = Rb[8];
    const float T0 = Tb[0], T1 = Tb[1], T2 = Tb[2];

    __shared__ float tsh[3 * NPTS];   // 12 KB
    if (sym) {
        const float* tb = targets + (size_t)b * 3 * NPTS;
        for (int k = tid; k < 3 * NPTS; k += THREADS) tsh[k] = tb[k];
        __syncthreads();
    }

    float acc = 0.0f;
    const int i = s * PTS_PER_BLK + tid;
    if (tid < PTS_PER_BLK && i < NPTS) {
        const float* mp = model_points + ((size_t)b * NPTS + i) * 3;
        const float m0 = mp[0], m1 = mp[1], m2 = mp[2];
        // p = R * m + t   (pred_r rows dot model point)
        const float px = fmaf(m0, R00, fmaf(m1, R01, fmaf(m2, R02, T0)));
        const float py = fmaf(m0, R10, fmaf(m1, R11, fmaf(m2, R12, T1)));
        const float pz = fmaf(m0, R20, fmaf(m1, R21, fmaf(m2, R22, T2)));

        float gx, gy, gz;
        if (sym) {
            float bestd = 3.4e38f;
            int   bestj = 0;
            #pragma unroll 4
            for (int j = 0; j < NPTS; ++j) {
                // loop counter is wave-uniform -> LDS broadcast reads
                const float dx = px - tsh[3 * j + 0];
                const float dy = py - tsh[3 * j + 1];
                const float dz = pz - tsh[3 * j + 2];
                const float d2 = fmaf(dx, dx, fmaf(dy, dy, dz * dz));
                if (d2 < bestd) { bestd = d2; bestj = j; }  // strict < = first-occurrence argmin
            }
            gx = tsh[3 * bestj + 0];
            gy = tsh[3 * bestj + 1];
            gz = tsh[3 * bestj + 2];
        } else {
            const float* tg = targets + ((size_t)b * NPTS + i) * 3;
            gx = tg[0]; gy = tg[1]; gz = tg[2];
        }
        const float dx = px - gx, dy = py - gy, dz = pz - gz;
        acc = sqrtf(fmaf(dx, dx, fmaf(dy, dy, dz * dz)));
    }

    // wave-64 reduce
    #pragma unroll
    for (int off = 32; off > 0; off >>= 1)
        acc += __shfl_down(acc, off, 64);

    __shared__ float wsum[THREADS / 64];
    const int wid = tid >> 6, lane = tid & 63;
    if (lane == 0) wsum[wid] = acc;
    __syncthreads();
    if (tid == 0) {
        float s2 = 0.0f;
        #pragma unroll
        for (int w = 0; w < THREADS / 64; ++w) s2 += wsum[w];
        atomicAdd(out, s2 * (1.0f / (BATCH * NPTS)));
    }
}

extern "C" void kernel_launch(void* const* d_in, const int* in_sizes, int n_in,
                              void* d_out, int out_size, void* d_ws, size_t ws_size,
                              hipStream_t stream) {
    const float* pred_r       = (const float*)d_in[0];
    const float* pred_t       = (const float*)d_in[1];
    const float* targets      = (const float*)d_in[2];
    const float* model_points = (const float*)d_in[3];
    const int*   idxs         = (const int*)d_in[4];
    float* out = (float*)d_out;

    // d_out is poisoned before every timed launch -> zero it (capture-safe)
    hipMemsetAsync(out, 0, sizeof(float) * out_size, stream);

    pose_loss_kernel<<<BATCH * SPLIT, THREADS, 0, stream>>>(
        pred_r, pred_t, targets, model_points, idxs, out);
}

// Round 2
// 96.330 us; speedup vs baseline: 1.0583x; 1.0583x over previous
//
#include <hip/hip_runtime.h>
#include <float.h>

// PoseLoss: pred = model @ R^T + t; NN(pred, targets) for symmetric ids
// {0,7,12,20}; loss = mean_b mean_n ||pred - tgt||. B=128, N=1000, fp32.
//
// Structure: grid = B * SPLIT blocks, 256 threads. Each block owns 64 points
// of one batch; each point is handled by a 4-lane quad that splits the
// 1000-target argmin scan into 4x250 chunks (shfl_xor combine, exact
// first-occurrence tie-break). Targets staged in LDS as float4 with w=|t|^2;
// scan uses d2' = |t|^2 - 2 p.t (same argmin as reference's p2+t2-2pt).

#define BATCH 128
#define NPTS  1000
#define SPLIT 16
#define PTS_PER_BLK 64          // points per block
#define LANES_PER_PT 4
#define JCHUNK (NPTS / LANES_PER_PT)   // 250
#define THREADS 256

__global__ __launch_bounds__(THREADS) void pose_loss_kernel(
    const float* __restrict__ pred_r,        // [B,3,3]
    const float* __restrict__ pred_t,        // [B,1,3]
    const float* __restrict__ targets,       // [B,N,3]
    const float* __restrict__ model_points,  // [B,N,3]
    const int*   __restrict__ idxs,          // [B]
    float* __restrict__ out)                 // [1]
{
    const int b   = blockIdx.x / SPLIT;
    const int s   = blockIdx.x % SPLIT;
    const int tid = threadIdx.x;

    const int id = idxs[b];
    const bool sym = (id == 0) | (id == 7) | (id == 12) | (id == 20);

    // batch-uniform R, t -> scalar loads
    const float* Rb = pred_r + b * 9;
    const float* Tb = pred_t + b * 3;
    const float R00 = Rb[0], R01 = Rb[1], R02 = Rb[2];
    const float R10 = Rb[3], R11 = Rb[4], R12 = Rb[5];
    const float R20 = Rb[6], R21 = Rb[7], R22 = Rb[8];
    const float T0 = Tb[0], T1 = Tb[1], T2 = Tb[2];

    __shared__ float4 tsh[NPTS];   // 16 KB, w = |t|^2
    if (sym) {
        const float* tb = targets + (size_t)b * 3 * NPTS;
        for (int k = tid; k < NPTS; k += THREADS) {
            const float x = tb[3 * k + 0];
            const float y = tb[3 * k + 1];
            const float z = tb[3 * k + 2];
            tsh[k] = make_float4(x, y, z, fmaf(x, x, fmaf(y, y, z * z)));
        }
        __syncthreads();
    }

    const int iloc = tid >> 2;        // 0..63
    const int sub  = tid & 3;         // lane within quad
    const int i    = s * PTS_PER_BLK + iloc;

    float acc = 0.0f;
    if (i < NPTS) {
        const float* mp = model_points + ((size_t)b * NPTS + i) * 3;
        const float m0 = mp[0], m1 = mp[1], m2 = mp[2];
        const float px = fmaf(m0, R00, fmaf(m1, R01, fmaf(m2, R02, T0)));
        const float py = fmaf(m0, R10, fmaf(m1, R11, fmaf(m2, R12, T1)));
        const float pz = fmaf(m0, R20, fmaf(m1, R21, fmaf(m2, R22, T2)));

        if (sym) {
            float bestd = FLT_MAX;
            int   bestj = sub * JCHUNK;
            const int j0 = sub * JCHUNK;
            #pragma unroll 5
            for (int j = j0; j < j0 + JCHUNK; ++j) {
                const float4 q = tsh[j];
                const float dot = fmaf(px, q.x, fmaf(py, q.y, pz * q.z));
                const float d2  = fmaf(-2.0f, dot, q.w);   // |t|^2 - 2 p.t
                if (d2 < bestd) { bestd = d2; bestj = j; } // strict < in-chunk
            }
            // quad combine: smaller d2 wins; tie -> smaller j (global
            // first-occurrence argmin, chunks are j-ordered by sub)
            #pragma unroll
            for (int off = 1; off < LANES_PER_PT; off <<= 1) {
                const float od = __shfl_xor(bestd, off, 64);
                const int   oj = __shfl_xor(bestj, off, 64);
                if (od < bestd || (od == bestd && oj < bestj)) {
                    bestd = od; bestj = oj;
                }
            }
            if (sub == 0) {
                const float4 q = tsh[bestj];
                const float dx = px - q.x, dy = py - q.y, dz = pz - q.z;
                acc = sqrtf(fmaf(dx, dx, fmaf(dy, dy, dz * dz)));
            }
        } else if (sub == 0) {
            const float* tg = targets + ((size_t)b * NPTS + i) * 3;
            const float dx = px - tg[0], dy = py - tg[1], dz = pz - tg[2];
            acc = sqrtf(fmaf(dx, dx, fmaf(dy, dy, dz * dz)));
        }
    }

    // wave-64 reduce
    #pragma unroll
    for (int off = 32; off > 0; off >>= 1)
        acc += __shfl_down(acc, off, 64);

    __shared__ float wsum[THREADS / 64];
    const int wid = tid >> 6, lane = tid & 63;
    if (lane == 0) wsum[wid] = acc;
    __syncthreads();
    if (tid == 0) {
        float s2 = 0.0f;
        #pragma unroll
        for (int w = 0; w < THREADS / 64; ++w) s2 += wsum[w];
        atomicAdd(out, s2 * (1.0f / (BATCH * NPTS)));
    }
}

extern "C" void kernel_launch(void* const* d_in, const int* in_sizes, int n_in,
                              void* d_out, int out_size, void* d_ws, size_t ws_size,
                              hipStream_t stream) {
    const float* pred_r       = (const float*)d_in[0];
    const float* pred_t       = (const float*)d_in[1];
    const float* targets      = (const float*)d_in[2];
    const float* model_points = (const float*)d_in[3];
    const int*   idxs         = (const int*)d_in[4];
    float* out = (float*)d_out;

    // d_out is poisoned before every timed launch -> zero it (capture-safe)
    hipMemsetAsync(out, 0, sizeof(float) * out_size, stream);

    pose_loss_kernel<<<BATCH * SPLIT, THREADS, 0, stream>>>(
        pred_r, pred_t, targets, model_points, idxs, out);
}

// Round 3
// 77.819 us; speedup vs baseline: 1.3100x; 1.2379x over previous
//
#include <hip/hip_runtime.h>
#include <float.h>

// PoseLoss: pred = model @ R^T + t; NN(pred, targets) for symmetric ids
// {0,7,12,20}; loss = mean_b mean_n ||pred - tgt||. B=128, N=1000, fp32.
//
// R3 changes vs R2:
//  - epilogue: per-block partial -> d_ws[bid] (plain store), second 1-block
//    kernel reduces 2048 partials. Removes 2048 same-address atomicAdds
//    (the R2 serialization suspect) and the d_out memset.
//  - 512 threads, 8 lanes/point -> 125-iteration argmin chunks (halved chain).

#define BATCH 128
#define NPTS  1000
#define SPLIT 16
#define PTS_PER_BLK 64                 // points per block
#define LANES_PER_PT 8
#define JCHUNK (NPTS / LANES_PER_PT)   // 125
#define THREADS 512
#define NBLK (BATCH * SPLIT)           // 2048

__global__ __launch_bounds__(THREADS) void pose_loss_kernel(
    const float* __restrict__ pred_r,        // [B,3,3]
    const float* __restrict__ pred_t,        // [B,1,3]
    const float* __restrict__ targets,       // [B,N,3]
    const float* __restrict__ model_points,  // [B,N,3]
    const int*   __restrict__ idxs,          // [B]
    float* __restrict__ partial)             // [NBLK]
{
    const int b   = blockIdx.x / SPLIT;
    const int s   = blockIdx.x % SPLIT;
    const int tid = threadIdx.x;

    const int id = idxs[b];
    const bool sym = (id == 0) | (id == 7) | (id == 12) | (id == 20);

    // batch-uniform R, t -> scalar loads
    const float* Rb = pred_r + b * 9;
    const float* Tb = pred_t + b * 3;
    const float R00 = Rb[0], R01 = Rb[1], R02 = Rb[2];
    const float R10 = Rb[3], R11 = Rb[4], R12 = Rb[5];
    const float R20 = Rb[6], R21 = Rb[7], R22 = Rb[8];
    const float T0 = Tb[0], T1 = Tb[1], T2 = Tb[2];

    __shared__ float4 tsh[NPTS];   // 16 KB, w = |t|^2
    if (sym) {
        const float* tb = targets + (size_t)b * 3 * NPTS;
        #pragma unroll
        for (int k = tid; k < NPTS; k += THREADS) {
            const float x = tb[3 * k + 0];
            const float y = tb[3 * k + 1];
            const float z = tb[3 * k + 2];
            tsh[k] = make_float4(x, y, z, fmaf(x, x, fmaf(y, y, z * z)));
        }
        __syncthreads();
    }

    const int iloc = tid >> 3;        // 0..63
    const int sub  = tid & 7;         // lane within octet
    const int i    = s * PTS_PER_BLK + iloc;

    float acc = 0.0f;
    if (i < NPTS) {
        const float* mp = model_points + ((size_t)b * NPTS + i) * 3;
        const float m0 = mp[0], m1 = mp[1], m2 = mp[2];
        const float px = fmaf(m0, R00, fmaf(m1, R01, fmaf(m2, R02, T0)));
        const float py = fmaf(m0, R10, fmaf(m1, R11, fmaf(m2, R12, T1)));
        const float pz = fmaf(m0, R20, fmaf(m1, R21, fmaf(m2, R22, T2)));

        if (sym) {
            float bestd = FLT_MAX;
            int   bestj = sub * JCHUNK;
            const int j0 = sub * JCHUNK;
            #pragma unroll 5
            for (int j = j0; j < j0 + JCHUNK; ++j) {
                const float4 q = tsh[j];   // uniform j per octet -> broadcast
                const float dot = fmaf(px, q.x, fmaf(py, q.y, pz * q.z));
                const float d2  = fmaf(-2.0f, dot, q.w);   // |t|^2 - 2 p.t
                if (d2 < bestd) { bestd = d2; bestj = j; } // strict < in-chunk
            }
            // octet combine: smaller d2; tie -> smaller j (first occurrence,
            // chunks are j-ordered by sub)
            #pragma unroll
            for (int off = 1; off < LANES_PER_PT; off <<= 1) {
                const float od = __shfl_xor(bestd, off, 64);
                const int   oj = __shfl_xor(bestj, off, 64);
                if (od < bestd || (od == bestd && oj < bestj)) {
                    bestd = od; bestj = oj;
                }
            }
            if (sub == 0) {
                const float4 q = tsh[bestj];
                const float dx = px - q.x, dy = py - q.y, dz = pz - q.z;
                acc = sqrtf(fmaf(dx, dx, fmaf(dy, dy, dz * dz)));
            }
        } else if (sub == 0) {
            const float* tg = targets + ((size_t)b * NPTS + i) * 3;
            const float dx = px - tg[0], dy = py - tg[1], dz = pz - tg[2];
            acc = sqrtf(fmaf(dx, dx, fmaf(dy, dy, dz * dz)));
        }
    }

    // wave-64 reduce
    #pragma unroll
    for (int off = 32; off > 0; off >>= 1)
        acc += __shfl_down(acc, off, 64);

    __shared__ float wsum[THREADS / 64];
    const int wid = tid >> 6, lane = tid & 63;
    if (lane == 0) wsum[wid] = acc;
    __syncthreads();
    if (tid == 0) {
        float s2 = 0.0f;
        #pragma unroll
        for (int w = 0; w < THREADS / 64; ++w) s2 += wsum[w];
        partial[blockIdx.x] = s2;    // plain store, no atomic
    }
}

__global__ __launch_bounds__(256) void pose_loss_reduce(
    const float* __restrict__ partial,   // [NBLK]
    float* __restrict__ out)             // [1]
{
    const int tid = threadIdx.x;
    float acc = 0.0f;
    #pragma unroll
    for (int k = tid; k < NBLK; k += 256) acc += partial[k];

    #pragma unroll
    for (int off = 32; off > 0; off >>= 1)
        acc += __shfl_down(acc, off, 64);

    __shared__ float wsum[4];
    const int wid = tid >> 6, lane = tid & 63;
    if (lane == 0) wsum[wid] = acc;
    __syncthreads();
    if (tid == 0) {
        float s2 = wsum[0] + wsum[1] + wsum[2] + wsum[3];
        out[0] = s2 * (1.0f / (BATCH * NPTS));
    }
}

extern "C" void kernel_launch(void* const* d_in, const int* in_sizes, int n_in,
                              void* d_out, int out_size, void* d_ws, size_t ws_size,
                              hipStream_t stream) {
    const float* pred_r       = (const float*)d_in[0];
    const float* pred_t       = (const float*)d_in[1];
    const float* targets      = (const float*)d_in[2];
    const float* model_points = (const float*)d_in[3];
    const int*   idxs         = (const int*)d_in[4];
    float* out     = (float*)d_out;
    float* partial = (float*)d_ws;   // NBLK floats; fully rewritten every call

    pose_loss_kernel<<<NBLK, THREADS, 0, stream>>>(
        pred_r, pred_t, targets, model_points, idxs, partial);
    pose_loss_reduce<<<1, 256, 0, stream>>>(partial, out);
}